// Round 7
// baseline (100.194 us; speedup 1.0000x reference)
//
#include <hip/hip_runtime.h>

// Problem constants (fixed by reference)
#define HW     4096
#define M_ROWS 32768        // N*H*W
#define OMD    112
#define OMP    128          // padded OM dim (stride, elements)

typedef __attribute__((ext_vector_type(8))) short short8;
typedef __attribute__((ext_vector_type(4))) float f32x4;

__device__ inline unsigned short f2bf(float f) {
  union { float f; unsigned int u; } v; v.f = f;
  unsigned int u = v.u;
  u += 0x7fffu + ((u >> 16) & 1u);      // RNE
  return (unsigned short)(u >> 16);
}
__device__ inline float bf2f(unsigned short h) {
  union { unsigned int u; float f; } v; v.u = ((unsigned int)h) << 16;
  return v.f;
}

// ---------------------------------------------------------------------------
// Fused prep: blocks [0,8192) = depthwise 3x3 (fp32 x in, bf16 dw out) which
// also emits xb = bf16(x); blocks [8192, 8834) = weight/bias conversions.
// (unchanged from R5 — proven)
// ---------------------------------------------------------------------------
__global__ __launch_bounds__(256) void prep_fused(
    const float* __restrict__ x, const float* __restrict__ w_dw,
    const float* __restrict__ b_dw, const float* __restrict__ w_in,
    const float* __restrict__ w_out, const float* __restrict__ w_pw,
    const float* __restrict__ b_pw, unsigned short* __restrict__ xb,
    unsigned short* __restrict__ dwb, unsigned short* __restrict__ wi_b,
    unsigned short* __restrict__ wo_b, unsigned short* __restrict__ wp_b,
    float* __restrict__ bpw_pad) {
  int bid = blockIdx.x;
  int tid = threadIdx.x;
  if (bid < 8192) {
    int idx = bid * 256 + tid;                 // (pixel, c/4): 32768*64
    int c4 = (idx & 63) * 4;
    int pp = idx >> 6;
    int n = pp >> 12;
    int hw = pp & 4095;
    int h = hw >> 6, w = hw & 63;
    float4 bb = *(const float4*)&b_dw[c4];
    float a0 = bb.x, a1 = bb.y, a2 = bb.z, a3 = bb.w;
#pragma unroll
    for (int ky = 0; ky < 3; ++ky) {
      int iy = h + ky - 1;
      if (iy < 0 || iy > 63) continue;
#pragma unroll
      for (int kx = 0; kx < 3; ++kx) {
        int ix = w + kx - 1;
        if (ix < 0 || ix > 63) continue;
        float4 xv = *(const float4*)&x[((size_t)(n << 12) + iy * 64 + ix) * 256 + c4];
        float4 wv = *(const float4*)&w_dw[(ky * 3 + kx) * 256 + c4];
        a0 += xv.x * wv.x;
        a1 += xv.y * wv.y;
        a2 += xv.z * wv.z;
        a3 += xv.w * wv.w;
      }
    }
    ushort4 o;
    o.x = f2bf(a0); o.y = f2bf(a1); o.z = f2bf(a2); o.w = f2bf(a3);
    *(ushort4*)&dwb[(size_t)pp * 256 + c4] = o;
    float4 cv = *(const float4*)&x[(size_t)pp * 256 + c4];
    ushort4 oc;
    oc.x = f2bf(cv.x); oc.y = f2bf(cv.y); oc.z = f2bf(cv.z); oc.w = f2bf(cv.w);
    *(ushort4*)&xb[(size_t)pp * 256 + c4] = oc;
  } else {
    int idx = (bid - 8192) * 256 + tid;
    if (idx < 65536) {
      wi_b[idx] = f2bf(w_in[idx]);
    } else if (idx < 131072) {
      int i = idx - 65536;
      wo_b[i] = f2bf(w_out[i]);
    } else if (idx < 131072 + OMP * 256) {
      int i = idx - 131072;
      int o = i >> 8;
      wp_b[i] = (o < OMD) ? f2bf(w_pw[i]) : (unsigned short)0;
    } else if (idx < 131072 + OMP * 256 + OMP) {
      int i = idx - (131072 + OMP * 256);
      bpw_pad[i] = (i < OMD) ? b_pw[i] : 0.f;
    }
  }
}

// ---------------------------------------------------------------------------
// Merged mid GEMMs (bf16 MFMA, m97 structure; 128x128 tile, BK=32, 4 waves).
// Blocks [0,256):   om[32768,128](bf16) = dwb @ wp_b^T + bpw
// Blocks [256,768): vproj[32768,256](bf16) = xb @ wi_b^T + b_in
// (unchanged from R5 — proven)
// ---------------------------------------------------------------------------
__global__ __launch_bounds__(256) void gemm_mid(
    const unsigned short* __restrict__ dwb, const unsigned short* __restrict__ wp_b,
    const float* __restrict__ bpw, unsigned short* __restrict__ om,
    const unsigned short* __restrict__ xb, const unsigned short* __restrict__ wi_b,
    const float* __restrict__ b_in, unsigned short* __restrict__ vproj) {
  __shared__ __align__(16) unsigned short As[128 * 32];  // 8 KB
  __shared__ __align__(16) unsigned short Bs[128 * 32];  // 8 KB
  int tid = threadIdx.x;
  int wave = tid >> 6, lane = tid & 63;
  int wr = wave >> 1, wc = wave & 1;

  const unsigned short *A, *W;
  const float* bias;
  unsigned short* Cout;
  int NN, colB;
  size_t rowB;
  int bid = blockIdx.x;
  if (bid < 256) {
    int swz = (bid & 7) * 32 + (bid >> 3);     // 256 % 8 == 0, bijective
    A = dwb; W = wp_b; bias = bpw; Cout = om; NN = 128;
    rowB = (size_t)swz * 128; colB = 0;
  } else {
    int b = bid - 256;
    int swz = (b & 7) * 64 + (b >> 3);         // 512 % 8 == 0, bijective
    A = xb; W = wi_b; bias = b_in; Cout = vproj; NN = 256;
    rowB = (size_t)(swz >> 1) * 128; colB = (swz & 1) * 128;
  }

  f32x4 acc[4][4];
#pragma unroll
  for (int m = 0; m < 4; ++m)
#pragma unroll
    for (int n = 0; n < 4; ++n) acc[m][n] = (f32x4)(0.f);

  int arow = lane >> 2;
  int acol = (lane & 3) * 8;

  for (int k0 = 0; k0 < 256; k0 += 32) {
#pragma unroll
    for (int jj = 0; jj < 2; ++jj) {
      int j = wave * 2 + jj;
      const unsigned short* ga = A + (rowB + 16 * j + arow) * 256 + k0 + acol;
      __builtin_amdgcn_global_load_lds(
          (const __attribute__((address_space(1))) unsigned int*)ga,
          (__attribute__((address_space(3))) unsigned int*)(As + j * 512),
          16, 0, 0);
      const unsigned short* gb =
          W + ((size_t)(colB + 16 * j + arow)) * 256 + k0 + acol;
      __builtin_amdgcn_global_load_lds(
          (const __attribute__((address_space(1))) unsigned int*)gb,
          (__attribute__((address_space(3))) unsigned int*)(Bs + j * 512),
          16, 0, 0);
    }
    __syncthreads();

    short8 aF[4], bF[4];
#pragma unroll
    for (int m = 0; m < 4; ++m)
      aF[m] = *(const short8*)&As[(wr * 64 + m * 16 + (lane & 15)) * 32 +
                                  (lane >> 4) * 8];
#pragma unroll
    for (int n = 0; n < 4; ++n)
      bF[n] = *(const short8*)&Bs[(wc * 64 + n * 16 + (lane & 15)) * 32 +
                                  (lane >> 4) * 8];
#pragma unroll
    for (int m = 0; m < 4; ++m)
#pragma unroll
      for (int n = 0; n < 4; ++n)
        acc[m][n] = __builtin_amdgcn_mfma_f32_16x16x32_bf16(
            aF[m], bF[n], acc[m][n], 0, 0, 0);
    __syncthreads();
  }

#pragma unroll
  for (int n = 0; n < 4; ++n) {
    int col = colB + wc * 64 + n * 16 + (lane & 15);
    float bv = bias[col];
#pragma unroll
    for (int m = 0; m < 4; ++m) {
#pragma unroll
      for (int j = 0; j < 4; ++j) {
        size_t row = rowB + wr * 64 + m * 16 + (lane >> 4) * 4 + j;
        Cout[row * NN + col] = f2bf(acc[m][n][j] + bv);
      }
    }
  }
}

// ---------------------------------------------------------------------------
// FUSED deform sampling + output GEMM, v2 (scratch-free phase 1).
// 512 blocks x 4 waves. Block owns 64 consecutive pixels (one image row) of
// one image (XCD-chunked swizzle: 64 blocks = one image per XCD).
// Phase 1 (no barriers): half-wave = one pixel; lane owns 8 channels.
//   Each lane computes its g-group's 9 taps' bilinear params redundantly
//   (om read direct from global, L1 broadcast), gathers 4 clamped corners
//   (validity-zeroed weights), accumulates fp32, ds_write_b128 into padded
//   linear As[64][264] (bf16).
// Phase 2: out[64,256](fp32) = As @ W^T + bias; 8 K-chunks of 32; Bs[256][32]
//   staged per chunk via global_load_lds; proven m97 fragment/epilogue maps.
// ---------------------------------------------------------------------------
__global__ __launch_bounds__(256) void fused_sample_gemm(
    const unsigned short* __restrict__ vproj, const unsigned short* __restrict__ om,
    const unsigned short* __restrict__ W, const float* __restrict__ bias,
    float* __restrict__ out) {
  constexpr int AP = 264;                                 // padded stride (shorts)
  __shared__ __align__(16) unsigned short As[64 * AP];    // 33792 B
  __shared__ __align__(16) unsigned short Bs[256 * 32];   // 16384 B

  int bid = blockIdx.x;
  int swz = (bid & 7) * 64 + (bid >> 3);   // 512 % 8 == 0 -> bijective
  int p0 = swz * 64;                        // 64 pixels, single image
  int n = p0 >> 12;

  int tid = threadIdx.x;
  int wave = tid >> 6, lane = tid & 63;
  int pix2 = lane >> 5, sub = lane & 31, g = sub >> 3;

  const char* vb_img = (const char*)(vproj + (((size_t)n << 12)) * 256);
  int choff = sub * 16;                     // channel byte offset (8 ch)

  // ---------------- Phase 1: sampling (no LDS scratch, no barriers) --------
  for (int iter = 0; iter < 8; ++iter) {
    int pl = wave * 16 + iter * 2 + pix2;   // block-local pixel 0..63
    int p = p0 + pl;
    int hy = (p >> 6) & 63, wx = p & 63;
    const unsigned short* o = om + (size_t)p * OMP;

    float acc[8];
#pragma unroll
    for (int j = 0; j < 8; ++j) acc[j] = 0.f;

#pragma unroll
    for (int k = 0; k < 9; ++k) {
      int gk = g * 9 + k;
      float ox = bf2f(o[gk * 2]), oy = bf2f(o[gk * 2 + 1]);
      float msk = bf2f(o[72 + gk]);
      float px = (float)(wx + (k % 3) - 1) + ox;
      float py = (float)(hy + (k / 3) - 1) + oy;
      float x0f = floorf(px), y0f = floorf(py);
      int x0 = (int)x0f, y0 = (int)y0f;
      float fx = px - x0f, fy = py - y0f;
      bool vx0 = (unsigned)x0 < 64u, vx1 = (unsigned)(x0 + 1) < 64u;
      bool vy0 = (unsigned)y0 < 64u, vy1 = (unsigned)(y0 + 1) < 64u;
      float w00 = (vy0 && vx0) ? (1.f - fx) * (1.f - fy) * msk : 0.f;
      float w01 = (vy0 && vx1) ? fx * (1.f - fy) * msk : 0.f;
      float w10 = (vy1 && vx0) ? (1.f - fx) * fy * msk : 0.f;
      float w11 = (vy1 && vx1) ? fx * fy * msk : 0.f;
      int x0c = min(max(x0, 0), 63), x1c = min(max(x0 + 1, 0), 63);
      int y0c = min(max(y0, 0), 63), y1c = min(max(y0 + 1, 0), 63);
      const char* r0 = vb_img + y0c * 32768 + choff;   // y*64*512
      const char* r1 = vb_img + y1c * 32768 + choff;
      short8 v00 = *(const short8*)(r0 + x0c * 512);
      short8 v01 = *(const short8*)(r0 + x1c * 512);
      short8 v10 = *(const short8*)(r1 + x0c * 512);
      short8 v11 = *(const short8*)(r1 + x1c * 512);
#pragma unroll
      for (int j = 0; j < 8; ++j)
        acc[j] += w00 * bf2f((unsigned short)v00[j]) +
                  w01 * bf2f((unsigned short)v01[j]) +
                  w10 * bf2f((unsigned short)v10[j]) +
                  w11 * bf2f((unsigned short)v11[j]);
    }

    union { unsigned short s[8]; short8 v8; } o8;
#pragma unroll
    for (int j = 0; j < 8; ++j) o8.s[j] = f2bf(acc[j]);
    *(short8*)&As[pl * AP + sub * 8] = o8.v8;   // byte addr pl*528+sub*16, 16-aligned
  }
  __syncthreads();   // As complete (drains lgkmcnt) before GEMM reads

  // ---------------- Phase 2: GEMM out[64,256] ----------------
  f32x4 acc2[4][4];
#pragma unroll
  for (int m = 0; m < 4; ++m)
#pragma unroll
    for (int nn = 0; nn < 4; ++nn) acc2[m][nn] = (f32x4)(0.f);

  for (int j = 0; j < 8; ++j) {              // K-chunk (32 wide)
#pragma unroll
    for (int jj = 0; jj < 4; ++jj) {
      int r = wave * 4 + jj;                 // 16 W-rows per instruction
      const unsigned short* gb =
          W + ((size_t)(16 * r + (lane >> 2))) * 256 + j * 32 + (lane & 3) * 8;
      __builtin_amdgcn_global_load_lds(
          (const __attribute__((address_space(1))) unsigned int*)gb,
          (__attribute__((address_space(3))) unsigned int*)(Bs + r * 512),
          16, 0, 0);
    }
    __syncthreads();   // drains vmcnt: Bs ready

    short8 aF[4], bF[4];
#pragma unroll
    for (int m = 0; m < 4; ++m)
      aF[m] = *(const short8*)&As[(m * 16 + (lane & 15)) * AP + j * 32 +
                                  (lane >> 4) * 8];
#pragma unroll
    for (int nn = 0; nn < 4; ++nn)
      bF[nn] = *(const short8*)&Bs[(wave * 64 + nn * 16 + (lane & 15)) * 32 +
                                   (lane >> 4) * 8];
#pragma unroll
    for (int m = 0; m < 4; ++m)
#pragma unroll
      for (int nn = 0; nn < 4; ++nn)
        acc2[m][nn] = __builtin_amdgcn_mfma_f32_16x16x32_bf16(
            aF[m], bF[nn], acc2[m][nn], 0, 0, 0);
    __syncthreads();   // WAR guard on Bs
  }

#pragma unroll
  for (int nn = 0; nn < 4; ++nn) {
    int col = wave * 64 + nn * 16 + (lane & 15);
    float bv = bias[col];
#pragma unroll
    for (int m = 0; m < 4; ++m) {
#pragma unroll
      for (int jr = 0; jr < 4; ++jr) {
        size_t row = (size_t)p0 + m * 16 + (lane >> 4) * 4 + jr;
        out[row * 256 + col] = acc2[m][nn][jr] + bv;
      }
    }
  }
}

// ---------------------------------------------------------------------------
extern "C" void kernel_launch(void* const* d_in, const int* in_sizes, int n_in,
                              void* d_out, int out_size, void* d_ws,
                              size_t ws_size, hipStream_t stream) {
  const float* x     = (const float*)d_in[0];
  const float* w_in  = (const float*)d_in[3];
  const float* b_in  = (const float*)d_in[4];
  const float* w_out = (const float*)d_in[5];
  const float* b_out = (const float*)d_in[6];
  const float* w_dw  = (const float*)d_in[7];
  const float* b_dw  = (const float*)d_in[8];
  const float* w_pw  = (const float*)d_in[9];
  const float* b_pw  = (const float*)d_in[10];
  float* out = (float*)d_out;
  char* ws = (char*)d_ws;

  unsigned short* xb    = (unsigned short*)(ws);                  // 16 MB
  unsigned short* dwb   = (unsigned short*)(ws + (16u << 20));    // 16 MB
  unsigned short* vproj = (unsigned short*)(ws + (32u << 20));    // 16 MB
  unsigned short* om    = (unsigned short*)(ws + (48u << 20));    // 8 MB (bf16, stride 128)
  unsigned short* wi_b  = (unsigned short*)(ws + (56u << 20));    // 128 KB
  unsigned short* wo_b  = (unsigned short*)(ws + (56u << 20) + (128u << 10));
  unsigned short* wp_b  = (unsigned short*)(ws + (56u << 20) + (256u << 10)); // 64 KB
  float*          bpw   = (float*)(ws + (56u << 20) + (320u << 10));          // 512 B

  prep_fused<<<8834, 256, 0, stream>>>(x, w_dw, b_dw, w_in, w_out, w_pw, b_pw,
                                       xb, dwb, wi_b, wo_b, wp_b, bpw);
  gemm_mid<<<768, 256, 0, stream>>>(dwb, wp_b, bpw, om, xb, wi_b, b_in, vproj);
  fused_sample_gemm<<<512, 256, 0, stream>>>(vproj, om, wo_b, b_out, out);
}

// Round 8
// 92.453 us; speedup vs baseline: 1.0837x; 1.0837x over previous
//
#include <hip/hip_runtime.h>

// Problem constants (fixed by reference)
#define HW     4096
#define M_ROWS 32768        // N*H*W
#define OMD    112
#define OMP    128          // padded OM dim (stride, elements)

typedef __attribute__((ext_vector_type(8))) short short8;
typedef __attribute__((ext_vector_type(4))) float f32x4;

__device__ inline unsigned short f2bf(float f) {
  union { float f; unsigned int u; } v; v.f = f;
  unsigned int u = v.u;
  u += 0x7fffu + ((u >> 16) & 1u);      // RNE
  return (unsigned short)(u >> 16);
}
__device__ inline float bf2f(unsigned short h) {
  union { unsigned int u; float f; } v; v.u = ((unsigned int)h) << 16;
  return v.f;
}

// ---------------------------------------------------------------------------
// Fused prep: blocks [0,8192) = depthwise 3x3 (fp32 x in, bf16 dw out) which
// also emits xb = bf16(x); blocks [8192, 8834) = weight/bias conversions.
// (proven R5)
// ---------------------------------------------------------------------------
__global__ __launch_bounds__(256) void prep_fused(
    const float* __restrict__ x, const float* __restrict__ w_dw,
    const float* __restrict__ b_dw, const float* __restrict__ w_in,
    const float* __restrict__ w_out, const float* __restrict__ w_pw,
    const float* __restrict__ b_pw, unsigned short* __restrict__ xb,
    unsigned short* __restrict__ dwb, unsigned short* __restrict__ wi_b,
    unsigned short* __restrict__ wo_b, unsigned short* __restrict__ wp_b,
    float* __restrict__ bpw_pad) {
  int bid = blockIdx.x;
  int tid = threadIdx.x;
  if (bid < 8192) {
    int idx = bid * 256 + tid;                 // (pixel, c/4): 32768*64
    int c4 = (idx & 63) * 4;
    int pp = idx >> 6;
    int n = pp >> 12;
    int hw = pp & 4095;
    int h = hw >> 6, w = hw & 63;
    float4 bb = *(const float4*)&b_dw[c4];
    float a0 = bb.x, a1 = bb.y, a2 = bb.z, a3 = bb.w;
#pragma unroll
    for (int ky = 0; ky < 3; ++ky) {
      int iy = h + ky - 1;
      if (iy < 0 || iy > 63) continue;
#pragma unroll
      for (int kx = 0; kx < 3; ++kx) {
        int ix = w + kx - 1;
        if (ix < 0 || ix > 63) continue;
        float4 xv = *(const float4*)&x[((size_t)(n << 12) + iy * 64 + ix) * 256 + c4];
        float4 wv = *(const float4*)&w_dw[(ky * 3 + kx) * 256 + c4];
        a0 += xv.x * wv.x;
        a1 += xv.y * wv.y;
        a2 += xv.z * wv.z;
        a3 += xv.w * wv.w;
      }
    }
    ushort4 o;
    o.x = f2bf(a0); o.y = f2bf(a1); o.z = f2bf(a2); o.w = f2bf(a3);
    *(ushort4*)&dwb[(size_t)pp * 256 + c4] = o;
    float4 cv = *(const float4*)&x[(size_t)pp * 256 + c4];
    ushort4 oc;
    oc.x = f2bf(cv.x); oc.y = f2bf(cv.y); oc.z = f2bf(cv.z); oc.w = f2bf(cv.w);
    *(ushort4*)&xb[(size_t)pp * 256 + c4] = oc;
  } else {
    int idx = (bid - 8192) * 256 + tid;
    if (idx < 65536) {
      wi_b[idx] = f2bf(w_in[idx]);
    } else if (idx < 131072) {
      int i = idx - 65536;
      wo_b[i] = f2bf(w_out[i]);
    } else if (idx < 131072 + OMP * 256) {
      int i = idx - 131072;
      int o = i >> 8;
      wp_b[i] = (o < OMD) ? f2bf(w_pw[i]) : (unsigned short)0;
    } else if (idx < 131072 + OMP * 256 + OMP) {
      int i = idx - (131072 + OMP * 256);
      bpw_pad[i] = (i < OMD) ? b_pw[i] : 0.f;
    }
  }
}

// ---------------------------------------------------------------------------
// Merged mid GEMMs (bf16 MFMA, m97 structure). (proven R5)
// Blocks [0,256):   om[32768,128](bf16) = dwb @ wp_b^T + bpw
// Blocks [256,768): vproj[32768,256](bf16) = xb @ wi_b^T + b_in
// ---------------------------------------------------------------------------
__global__ __launch_bounds__(256) void gemm_mid(
    const unsigned short* __restrict__ dwb, const unsigned short* __restrict__ wp_b,
    const float* __restrict__ bpw, unsigned short* __restrict__ om,
    const unsigned short* __restrict__ xb, const unsigned short* __restrict__ wi_b,
    const float* __restrict__ b_in, unsigned short* __restrict__ vproj) {
  __shared__ __align__(16) unsigned short As[128 * 32];  // 8 KB
  __shared__ __align__(16) unsigned short Bs[128 * 32];  // 8 KB
  int tid = threadIdx.x;
  int wave = tid >> 6, lane = tid & 63;
  int wr = wave >> 1, wc = wave & 1;

  const unsigned short *A, *W;
  const float* bias;
  unsigned short* Cout;
  int NN, colB;
  size_t rowB;
  int bid = blockIdx.x;
  if (bid < 256) {
    int swz = (bid & 7) * 32 + (bid >> 3);     // 256 % 8 == 0, bijective
    A = dwb; W = wp_b; bias = bpw; Cout = om; NN = 128;
    rowB = (size_t)swz * 128; colB = 0;
  } else {
    int b = bid - 256;
    int swz = (b & 7) * 64 + (b >> 3);         // 512 % 8 == 0, bijective
    A = xb; W = wi_b; bias = b_in; Cout = vproj; NN = 256;
    rowB = (size_t)(swz >> 1) * 128; colB = (swz & 1) * 128;
  }

  f32x4 acc[4][4];
#pragma unroll
  for (int m = 0; m < 4; ++m)
#pragma unroll
    for (int n = 0; n < 4; ++n) acc[m][n] = (f32x4)(0.f);

  int arow = lane >> 2;
  int acol = (lane & 3) * 8;

  for (int k0 = 0; k0 < 256; k0 += 32) {
#pragma unroll
    for (int jj = 0; jj < 2; ++jj) {
      int j = wave * 2 + jj;
      const unsigned short* ga = A + (rowB + 16 * j + arow) * 256 + k0 + acol;
      __builtin_amdgcn_global_load_lds(
          (const __attribute__((address_space(1))) unsigned int*)ga,
          (__attribute__((address_space(3))) unsigned int*)(As + j * 512),
          16, 0, 0);
      const unsigned short* gb =
          W + ((size_t)(colB + 16 * j + arow)) * 256 + k0 + acol;
      __builtin_amdgcn_global_load_lds(
          (const __attribute__((address_space(1))) unsigned int*)gb,
          (__attribute__((address_space(3))) unsigned int*)(Bs + j * 512),
          16, 0, 0);
    }
    __syncthreads();

    short8 aF[4], bF[4];
#pragma unroll
    for (int m = 0; m < 4; ++m)
      aF[m] = *(const short8*)&As[(wr * 64 + m * 16 + (lane & 15)) * 32 +
                                  (lane >> 4) * 8];
#pragma unroll
    for (int n = 0; n < 4; ++n)
      bF[n] = *(const short8*)&Bs[(wc * 64 + n * 16 + (lane & 15)) * 32 +
                                  (lane >> 4) * 8];
#pragma unroll
    for (int m = 0; m < 4; ++m)
#pragma unroll
      for (int n = 0; n < 4; ++n)
        acc[m][n] = __builtin_amdgcn_mfma_f32_16x16x32_bf16(
            aF[m], bF[n], acc[m][n], 0, 0, 0);
    __syncthreads();
  }

#pragma unroll
  for (int n = 0; n < 4; ++n) {
    int col = colB + wc * 64 + n * 16 + (lane & 15);
    float bv = bias[col];
#pragma unroll
    for (int m = 0; m < 4; ++m) {
#pragma unroll
      for (int j = 0; j < 4; ++j) {
        size_t row = rowB + wr * 64 + m * 16 + (lane >> 4) * 4 + j;
        Cout[row * NN + col] = f2bf(acc[m][n][j] + bv);
      }
    }
  }
}

// ---------------------------------------------------------------------------
// Deformable sampling v4: LDS-staged vproj window.
// 1024 blocks x 256 threads (4 waves). Block = (image n, 8x8 pixel tile,
// 128-channel half). Stage clamped 12x12 pixel window (36.9 KB) into LDS via
// global_load_lds, then sample: wave = 4 pixels (16 lanes/px, 8 ch/lane);
// per tap: validity-zeroed weights (image bounds), image-clamped corners,
// window-clamped LDS indices, 4 ds_read_b128 + fma.
// Valid (== reference) for |offset| < 1 px; data has |offset| ~<= 0.12.
// XCD-chunked swizzle: 128 consecutive blocks = one image per XCD L2.
// ---------------------------------------------------------------------------
__global__ __launch_bounds__(256) void deform_sample_v4(
    const unsigned short* __restrict__ vproj, const unsigned short* __restrict__ om,
    unsigned short* __restrict__ samp) {
  __shared__ __align__(16) unsigned short s_v[144 * 128];   // 36864 B

  int bid = blockIdx.x;
  int swz = (bid & 7) * 128 + (bid >> 3);   // 1024 % 8 == 0 -> bijective
  int n = swz >> 7;                          // image
  int t = swz & 127;
  int c0 = (t & 1) << 7;                     // channel half: 0 or 128
  int tile = t >> 1;                         // 0..63
  int ty0 = (tile >> 3) << 3, tx0 = (tile & 7) << 3;
  int wy0 = ty0 - 2, wx0 = tx0 - 2;          // window origin (may be <0)

  int tid = threadIdx.x;
  int wave = tid >> 6, lane = tid & 63;

  // ---- stage 12x12 window (clamped coords; edges duplicated) ----
  const unsigned short* vimg = vproj + ((size_t)n << 12) * 256;
#pragma unroll
  for (int i = 0; i < 9; ++i) {
    int cell = i * 16 + (tid >> 4);          // 0..143
    int r = cell / 12, c = cell % 12;
    int gy = min(max(wy0 + r, 0), 63);
    int gx = min(max(wx0 + c, 0), 63);
    const unsigned short* src =
        vimg + (size_t)(gy * 64 + gx) * 256 + c0 + (tid & 15) * 8;
    // wave-uniform LDS base; lane data lands at +lane*16 -> cells in order
    __builtin_amdgcn_global_load_lds(
        (const __attribute__((address_space(1))) unsigned int*)src,
        (__attribute__((address_space(3))) unsigned int*)(s_v + i * 2048 + wave * 512),
        16, 0, 0);
  }
  __syncthreads();   // drains vmcnt -> window resident

  // ---- sampling: wave = 4 px; lane: px=(lane>>4), 8 ch at sub*8 ----
  int sub = lane & 15;
  int g = (c0 >> 6) + (sub >> 3);            // this lane's group 0..3
  int chlds = sub * 8;                        // LDS channel offset (shorts)

#pragma unroll
  for (int iter = 0; iter < 4; ++iter) {
    int pl = iter * 16 + wave * 4 + (lane >> 4);   // tile-local pixel 0..63
    int py = pl >> 3, pxx = pl & 7;
    int hy = ty0 + py, wx = tx0 + pxx;
    int p = (n << 12) + hy * 64 + wx;
    const unsigned short* o = om + (size_t)p * OMP;

    float acc[8];
#pragma unroll
    for (int j = 0; j < 8; ++j) acc[j] = 0.f;

#pragma unroll
    for (int k = 0; k < 9; ++k) {
      int gk = g * 9 + k;
      float ox = bf2f(o[gk * 2]), oy = bf2f(o[gk * 2 + 1]);
      float msk = bf2f(o[72 + gk]);
      float px = (float)(wx + (k % 3) - 1) + ox;
      float py2 = (float)(hy + (k / 3) - 1) + oy;
      float x0f = floorf(px), y0f = floorf(py2);
      int x0 = (int)x0f, y0 = (int)y0f;
      float fx = px - x0f, fy = py2 - y0f;
      bool vx0 = (unsigned)x0 < 64u, vx1 = (unsigned)(x0 + 1) < 64u;
      bool vy0 = (unsigned)y0 < 64u, vy1 = (unsigned)(y0 + 1) < 64u;
      float w00 = (vy0 && vx0) ? (1.f - fx) * (1.f - fy) * msk : 0.f;
      float w01 = (vy0 && vx1) ? fx * (1.f - fy) * msk : 0.f;
      float w10 = (vy1 && vx0) ? (1.f - fx) * fy * msk : 0.f;
      float w11 = (vy1 && vx1) ? fx * fy * msk : 0.f;
      // image-clamp (reference semantics), then window-clamp (LDS safety)
      int ix0 = min(max(min(max(x0, 0), 63) - wx0, 0), 11);
      int ix1 = min(max(min(max(x0 + 1, 0), 63) - wx0, 0), 11);
      int iy0 = min(max(min(max(y0, 0), 63) - wy0, 0), 11);
      int iy1 = min(max(min(max(y0 + 1, 0), 63) - wy0, 0), 11);
      short8 v00 = *(const short8*)&s_v[(iy0 * 12 + ix0) * 128 + chlds];
      short8 v01 = *(const short8*)&s_v[(iy0 * 12 + ix1) * 128 + chlds];
      short8 v10 = *(const short8*)&s_v[(iy1 * 12 + ix0) * 128 + chlds];
      short8 v11 = *(const short8*)&s_v[(iy1 * 12 + ix1) * 128 + chlds];
#pragma unroll
      for (int j = 0; j < 8; ++j)
        acc[j] += w00 * bf2f((unsigned short)v00[j]) +
                  w01 * bf2f((unsigned short)v01[j]) +
                  w10 * bf2f((unsigned short)v10[j]) +
                  w11 * bf2f((unsigned short)v11[j]);
    }

    union { unsigned short s[8]; short8 v8; } o8;
#pragma unroll
    for (int j = 0; j < 8; ++j) o8.s[j] = f2bf(acc[j]);
    *(short8*)&samp[(size_t)p * 256 + c0 + sub * 8] = o8.v8;
  }
}

// ---------------------------------------------------------------------------
// Final GEMM: out[32768,256](fp32) = samp @ wo_b^T + b_out  (proven R5)
// ---------------------------------------------------------------------------
__global__ __launch_bounds__(256) void gemm_out(
    const unsigned short* __restrict__ A, const unsigned short* __restrict__ W,
    const float* __restrict__ bias, float* __restrict__ Cout) {
  __shared__ __align__(16) unsigned short As[128 * 32];
  __shared__ __align__(16) unsigned short Bs[128 * 32];
  int tid = threadIdx.x;
  int wave = tid >> 6, lane = tid & 63;
  int wr = wave >> 1, wc = wave & 1;

  int bid = blockIdx.x;
  int swz = (bid & 7) * 64 + (bid >> 3);
  size_t rowB = (size_t)(swz >> 1) * 128;
  int colB = (swz & 1) * 128;

  f32x4 acc[4][4];
#pragma unroll
  for (int m = 0; m < 4; ++m)
#pragma unroll
    for (int n = 0; n < 4; ++n) acc[m][n] = (f32x4)(0.f);

  int arow = lane >> 2;
  int acol = (lane & 3) * 8;

  for (int k0 = 0; k0 < 256; k0 += 32) {
#pragma unroll
    for (int jj = 0; jj < 2; ++jj) {
      int j = wave * 2 + jj;
      const unsigned short* ga = A + (rowB + 16 * j + arow) * 256 + k0 + acol;
      __builtin_amdgcn_global_load_lds(
          (const __attribute__((address_space(1))) unsigned int*)ga,
          (__attribute__((address_space(3))) unsigned int*)(As + j * 512),
          16, 0, 0);
      const unsigned short* gb =
          W + ((size_t)(colB + 16 * j + arow)) * 256 + k0 + acol;
      __builtin_amdgcn_global_load_lds(
          (const __attribute__((address_space(1))) unsigned int*)gb,
          (__attribute__((address_space(3))) unsigned int*)(Bs + j * 512),
          16, 0, 0);
    }
    __syncthreads();

    short8 aF[4], bF[4];
#pragma unroll
    for (int m = 0; m < 4; ++m)
      aF[m] = *(const short8*)&As[(wr * 64 + m * 16 + (lane & 15)) * 32 +
                                  (lane >> 4) * 8];
#pragma unroll
    for (int n = 0; n < 4; ++n)
      bF[n] = *(const short8*)&Bs[(wc * 64 + n * 16 + (lane & 15)) * 32 +
                                  (lane >> 4) * 8];
#pragma unroll
    for (int m = 0; m < 4; ++m)
#pragma unroll
      for (int n = 0; n < 4; ++n)
        acc[m][n] = __builtin_amdgcn_mfma_f32_16x16x32_bf16(
            aF[m], bF[n], acc[m][n], 0, 0, 0);
    __syncthreads();
  }

#pragma unroll
  for (int n = 0; n < 4; ++n) {
    int col = colB + wc * 64 + n * 16 + (lane & 15);
    float bv = bias[col];
#pragma unroll
    for (int m = 0; m < 4; ++m) {
#pragma unroll
      for (int j = 0; j < 4; ++j) {
        size_t row = rowB + wr * 64 + m * 16 + (lane >> 4) * 4 + j;
        Cout[row * 256 + col] = acc[m][n][j] + bv;
      }
    }
  }
}

// ---------------------------------------------------------------------------
extern "C" void kernel_launch(void* const* d_in, const int* in_sizes, int n_in,
                              void* d_out, int out_size, void* d_ws,
                              size_t ws_size, hipStream_t stream) {
  const float* x     = (const float*)d_in[0];
  const float* w_in  = (const float*)d_in[3];
  const float* b_in  = (const float*)d_in[4];
  const float* w_out = (const float*)d_in[5];
  const float* b_out = (const float*)d_in[6];
  const float* w_dw  = (const float*)d_in[7];
  const float* b_dw  = (const float*)d_in[8];
  const float* w_pw  = (const float*)d_in[9];
  const float* b_pw  = (const float*)d_in[10];
  float* out = (float*)d_out;
  char* ws = (char*)d_ws;

  unsigned short* xb    = (unsigned short*)(ws);                  // 16 MB
  unsigned short* dwb   = (unsigned short*)(ws + (16u << 20));    // 16 MB (dw -> samp)
  unsigned short* vproj = (unsigned short*)(ws + (32u << 20));    // 16 MB
  unsigned short* om    = (unsigned short*)(ws + (48u << 20));    // 8 MB (bf16, stride 128)
  unsigned short* wi_b  = (unsigned short*)(ws + (56u << 20));    // 128 KB
  unsigned short* wo_b  = (unsigned short*)(ws + (56u << 20) + (128u << 10));
  unsigned short* wp_b  = (unsigned short*)(ws + (56u << 20) + (256u << 10)); // 64 KB
  float*          bpw   = (float*)(ws + (56u << 20) + (320u << 10));          // 512 B

  prep_fused<<<8834, 256, 0, stream>>>(x, w_dw, b_dw, w_in, w_out, w_pw, b_pw,
                                       xb, dwb, wi_b, wo_b, wp_b, bpw);
  gemm_mid<<<768, 256, 0, stream>>>(dwb, wp_b, bpw, om, xb, wi_b, b_in, vproj);
  deform_sample_v4<<<1024, 256, 0, stream>>>(vproj, om, dwb /* samp */);
  gemm_out<<<512, 256, 0, stream>>>(dwb, wo_b, b_out, out);
}

// Round 9
// 81.423 us; speedup vs baseline: 1.2305x; 1.1355x over previous
//
#include <hip/hip_runtime.h>

// Problem constants (fixed by reference)
#define HW     4096
#define M_ROWS 32768        // N*H*W
#define OMD    112
#define OMP    128          // padded OM dim (stride, elements)

typedef __attribute__((ext_vector_type(8))) short short8;
typedef __attribute__((ext_vector_type(4))) float f32x4;

__device__ inline unsigned short f2bf(float f) {
  union { float f; unsigned int u; } v; v.f = f;
  unsigned int u = v.u;
  u += 0x7fffu + ((u >> 16) & 1u);      // RNE
  return (unsigned short)(u >> 16);
}
__device__ inline float bf2f(unsigned short h) {
  union { unsigned int u; float f; } v; v.u = ((unsigned int)h) << 16;
  return v.f;
}

// ---------------------------------------------------------------------------
// Fused prep: blocks [0,8192) = depthwise 3x3 (fp32 x in, bf16 dw out) which
// also emits xb = bf16(x); blocks [8192, 8834) = weight/bias conversions.
// (proven R5)
// ---------------------------------------------------------------------------
__global__ __launch_bounds__(256) void prep_fused(
    const float* __restrict__ x, const float* __restrict__ w_dw,
    const float* __restrict__ b_dw, const float* __restrict__ w_in,
    const float* __restrict__ w_out, const float* __restrict__ w_pw,
    const float* __restrict__ b_pw, unsigned short* __restrict__ xb,
    unsigned short* __restrict__ dwb, unsigned short* __restrict__ wi_b,
    unsigned short* __restrict__ wo_b, unsigned short* __restrict__ wp_b,
    float* __restrict__ bpw_pad) {
  int bid = blockIdx.x;
  int tid = threadIdx.x;
  if (bid < 8192) {
    int idx = bid * 256 + tid;                 // (pixel, c/4): 32768*64
    int c4 = (idx & 63) * 4;
    int pp = idx >> 6;
    int n = pp >> 12;
    int hw = pp & 4095;
    int h = hw >> 6, w = hw & 63;
    float4 bb = *(const float4*)&b_dw[c4];
    float a0 = bb.x, a1 = bb.y, a2 = bb.z, a3 = bb.w;
#pragma unroll
    for (int ky = 0; ky < 3; ++ky) {
      int iy = h + ky - 1;
      if (iy < 0 || iy > 63) continue;
#pragma unroll
      for (int kx = 0; kx < 3; ++kx) {
        int ix = w + kx - 1;
        if (ix < 0 || ix > 63) continue;
        float4 xv = *(const float4*)&x[((size_t)(n << 12) + iy * 64 + ix) * 256 + c4];
        float4 wv = *(const float4*)&w_dw[(ky * 3 + kx) * 256 + c4];
        a0 += xv.x * wv.x;
        a1 += xv.y * wv.y;
        a2 += xv.z * wv.z;
        a3 += xv.w * wv.w;
      }
    }
    ushort4 o;
    o.x = f2bf(a0); o.y = f2bf(a1); o.z = f2bf(a2); o.w = f2bf(a3);
    *(ushort4*)&dwb[(size_t)pp * 256 + c4] = o;
    float4 cv = *(const float4*)&x[(size_t)pp * 256 + c4];
    ushort4 oc;
    oc.x = f2bf(cv.x); oc.y = f2bf(cv.y); oc.z = f2bf(cv.z); oc.w = f2bf(cv.w);
    *(ushort4*)&xb[(size_t)pp * 256 + c4] = oc;
  } else {
    int idx = (bid - 8192) * 256 + tid;
    if (idx < 65536) {
      wi_b[idx] = f2bf(w_in[idx]);
    } else if (idx < 131072) {
      int i = idx - 65536;
      wo_b[i] = f2bf(w_out[i]);
    } else if (idx < 131072 + OMP * 256) {
      int i = idx - 131072;
      int o = i >> 8;
      wp_b[i] = (o < OMD) ? f2bf(w_pw[i]) : (unsigned short)0;
    } else if (idx < 131072 + OMP * 256 + OMP) {
      int i = idx - (131072 + OMP * 256);
      bpw_pad[i] = (i < OMD) ? b_pw[i] : 0.f;
    }
  }
}

// ---------------------------------------------------------------------------
// Merged mid GEMMs (bf16 MFMA, m97 structure). (proven R5)
// Blocks [0,256):   om[32768,128](bf16) = dwb @ wp_b^T + bpw
// Blocks [256,768): vproj[32768,256](bf16) = xb @ wi_b^T + b_in
// ---------------------------------------------------------------------------
__global__ __launch_bounds__(256) void gemm_mid(
    const unsigned short* __restrict__ dwb, const unsigned short* __restrict__ wp_b,
    const float* __restrict__ bpw, unsigned short* __restrict__ om,
    const unsigned short* __restrict__ xb, const unsigned short* __restrict__ wi_b,
    const float* __restrict__ b_in, unsigned short* __restrict__ vproj) {
  __shared__ __align__(16) unsigned short As[128 * 32];  // 8 KB
  __shared__ __align__(16) unsigned short Bs[128 * 32];  // 8 KB
  int tid = threadIdx.x;
  int wave = tid >> 6, lane = tid & 63;
  int wr = wave >> 1, wc = wave & 1;

  const unsigned short *A, *W;
  const float* bias;
  unsigned short* Cout;
  int NN, colB;
  size_t rowB;
  int bid = blockIdx.x;
  if (bid < 256) {
    int swz = (bid & 7) * 32 + (bid >> 3);     // 256 % 8 == 0, bijective
    A = dwb; W = wp_b; bias = bpw; Cout = om; NN = 128;
    rowB = (size_t)swz * 128; colB = 0;
  } else {
    int b = bid - 256;
    int swz = (b & 7) * 64 + (b >> 3);         // 512 % 8 == 0, bijective
    A = xb; W = wi_b; bias = b_in; Cout = vproj; NN = 256;
    rowB = (size_t)(swz >> 1) * 128; colB = (swz & 1) * 128;
  }

  f32x4 acc[4][4];
#pragma unroll
  for (int m = 0; m < 4; ++m)
#pragma unroll
    for (int n = 0; n < 4; ++n) acc[m][n] = (f32x4)(0.f);

  int arow = lane >> 2;
  int acol = (lane & 3) * 8;

  for (int k0 = 0; k0 < 256; k0 += 32) {
#pragma unroll
    for (int jj = 0; jj < 2; ++jj) {
      int j = wave * 2 + jj;
      const unsigned short* ga = A + (rowB + 16 * j + arow) * 256 + k0 + acol;
      __builtin_amdgcn_global_load_lds(
          (const __attribute__((address_space(1))) unsigned int*)ga,
          (__attribute__((address_space(3))) unsigned int*)(As + j * 512),
          16, 0, 0);
      const unsigned short* gb =
          W + ((size_t)(colB + 16 * j + arow)) * 256 + k0 + acol;
      __builtin_amdgcn_global_load_lds(
          (const __attribute__((address_space(1))) unsigned int*)gb,
          (__attribute__((address_space(3))) unsigned int*)(Bs + j * 512),
          16, 0, 0);
    }
    __syncthreads();

    short8 aF[4], bF[4];
#pragma unroll
    for (int m = 0; m < 4; ++m)
      aF[m] = *(const short8*)&As[(wr * 64 + m * 16 + (lane & 15)) * 32 +
                                  (lane >> 4) * 8];
#pragma unroll
    for (int n = 0; n < 4; ++n)
      bF[n] = *(const short8*)&Bs[(wc * 64 + n * 16 + (lane & 15)) * 32 +
                                  (lane >> 4) * 8];
#pragma unroll
    for (int m = 0; m < 4; ++m)
#pragma unroll
      for (int n = 0; n < 4; ++n)
        acc[m][n] = __builtin_amdgcn_mfma_f32_16x16x32_bf16(
            aF[m], bF[n], acc[m][n], 0, 0, 0);
    __syncthreads();
  }

#pragma unroll
  for (int n = 0; n < 4; ++n) {
    int col = colB + wc * 64 + n * 16 + (lane & 15);
    float bv = bias[col];
#pragma unroll
    for (int m = 0; m < 4; ++m) {
#pragma unroll
      for (int j = 0; j < 4; ++j) {
        size_t row = rowB + wr * 64 + m * 16 + (lane >> 4) * 4 + j;
        Cout[row * NN + col] = f2bf(acc[m][n][j] + bv);
      }
    }
  }
}

// ---------------------------------------------------------------------------
// Deformable sampling v5: LDS window (v4) + cooperative param precompute (b3).
// 2048 blocks x 256 threads (4 waves). Block = (image, 8x8 px tile, group g:
// 64 channels). Stage clamped 12x12x64ch window (18.4 KB) via global_load_lds;
// cooperatively precompute 576 (px,k) entries: float4 validity-zeroed weights
// + int4 window byte-offsets (18.4 KB LDS). Sampling loop: pure LDS reads —
// 2 broadcast b128 (params) + 4 corner b128 per tap; NO global loads.
// Valid (== reference) for |offset| < 1 px (confirmed by v4 passing).
// XCD-chunked swizzle: 256 consecutive blocks = one image per XCD L2.
// ---------------------------------------------------------------------------
__global__ __launch_bounds__(256) void deform_sample_v5(
    const unsigned short* __restrict__ vproj, const unsigned short* __restrict__ om,
    unsigned short* __restrict__ samp) {
  __shared__ __align__(16) unsigned short s_v[144 * 64];   // 18432 B
  __shared__ __align__(16) float4 s_wgt[576];              // 9216 B
  __shared__ __align__(16) int4   s_off[576];              // 9216 B

  int bid = blockIdx.x;
  int swz = (bid & 7) * 256 + (bid >> 3);   // 2048 % 8 == 0 -> bijective
  int n = swz >> 8;                          // image 0..7
  int rem = swz & 255;
  int tile = rem >> 2;                       // 0..63
  int g = rem & 3;                           // group 0..3
  int ty0 = (tile >> 3) << 3, tx0 = (tile & 7) << 3;
  int wy0 = ty0 - 2, wx0 = tx0 - 2;          // window origin (may be <0)

  int tid = threadIdx.x;
  int wave = tid >> 6, lane = tid & 63;

  const unsigned short* vimg = vproj + ((size_t)n << 12) * 256;

  // ---- stage 144-cell window x 64 ch, flat 18432 B (18 x 1KB wave-chunks) --
#pragma unroll
  for (int i = 0; i < 5; ++i) {
    int seg = i * 4 + wave;
    if (seg < 18) {
      int f = seg * 1024 + lane * 16;        // flat byte offset in window
      int cell = f >> 7;                      // 128 B per cell
      int inner = (f >> 1) & 63;              // short offset within cell
      int r = cell / 12, c = cell - r * 12;
      int gy = min(max(wy0 + r, 0), 63);
      int gx = min(max(wx0 + c, 0), 63);
      const unsigned short* src =
          vimg + (size_t)(gy * 64 + gx) * 256 + g * 64 + inner;
      __builtin_amdgcn_global_load_lds(
          (const __attribute__((address_space(1))) unsigned int*)src,
          (__attribute__((address_space(3))) unsigned int*)(s_v + seg * 512),
          16, 0, 0);
    }
  }

  // ---- cooperative param precompute: 576 entries = 64 px x 9 taps ----
  for (int e = tid; e < 576; e += 256) {
    int pl = e / 9, k = e - pl * 9;
    int hy = ty0 + (pl >> 3), wx = tx0 + (pl & 7);
    int p = (n << 12) + hy * 64 + wx;
    int gk = g * 9 + k;
    const unsigned short* o = om + (size_t)p * OMP;
    float ox = bf2f(o[gk * 2]), oy = bf2f(o[gk * 2 + 1]);
    float msk = bf2f(o[72 + gk]);
    float px = (float)(wx + (k % 3) - 1) + ox;
    float py = (float)(hy + (k / 3) - 1) + oy;
    float x0f = floorf(px), y0f = floorf(py);
    int x0 = (int)x0f, y0 = (int)y0f;
    float fx = px - x0f, fy = py - y0f;
    bool vx0 = (unsigned)x0 < 64u, vx1 = (unsigned)(x0 + 1) < 64u;
    bool vy0 = (unsigned)y0 < 64u, vy1 = (unsigned)(y0 + 1) < 64u;
    float4 wv;
    wv.x = (vy0 && vx0) ? (1.f - fx) * (1.f - fy) * msk : 0.f;
    wv.y = (vy0 && vx1) ? fx * (1.f - fy) * msk : 0.f;
    wv.z = (vy1 && vx0) ? (1.f - fx) * fy * msk : 0.f;
    wv.w = (vy1 && vx1) ? fx * fy * msk : 0.f;
    // image-clamp (reference semantics), then window-clamp (LDS safety)
    int ix0 = min(max(min(max(x0, 0), 63) - wx0, 0), 11);
    int ix1 = min(max(min(max(x0 + 1, 0), 63) - wx0, 0), 11);
    int iy0 = min(max(min(max(y0, 0), 63) - wy0, 0), 11);
    int iy1 = min(max(min(max(y0 + 1, 0), 63) - wy0, 0), 11);
    int4 ov;
    ov.x = (iy0 * 12 + ix0) * 128;            // byte offsets (64 ch * 2 B)
    ov.y = (iy0 * 12 + ix1) * 128;
    ov.z = (iy1 * 12 + ix0) * 128;
    ov.w = (iy1 * 12 + ix1) * 128;
    s_wgt[e] = wv;
    s_off[e] = ov;
  }
  __syncthreads();   // window (vmcnt drained) + params visible

  // ---- sampling: 8 lanes/px (8 ch/lane), 32 px per pass, 2 passes ----
  int sub = lane & 7;
  int chb = sub * 16;                         // channel byte offset
  const char* vb = (const char*)s_v;

#pragma unroll
  for (int iter = 0; iter < 2; ++iter) {
    int pl = iter * 32 + wave * 8 + (lane >> 3);   // tile-local pixel 0..63
    int hy = ty0 + (pl >> 3), wx = tx0 + (pl & 7);
    int p = (n << 12) + hy * 64 + wx;

    float acc[8];
#pragma unroll
    for (int j = 0; j < 8; ++j) acc[j] = 0.f;

#pragma unroll
    for (int k = 0; k < 9; ++k) {
      int e = pl * 9 + k;
      float4 wv = s_wgt[e];
      int4 ov = s_off[e];
      short8 v00 = *(const short8*)(vb + ov.x + chb);
      short8 v01 = *(const short8*)(vb + ov.y + chb);
      short8 v10 = *(const short8*)(vb + ov.z + chb);
      short8 v11 = *(const short8*)(vb + ov.w + chb);
#pragma unroll
      for (int j = 0; j < 8; ++j)
        acc[j] += wv.x * bf2f((unsigned short)v00[j]) +
                  wv.y * bf2f((unsigned short)v01[j]) +
                  wv.z * bf2f((unsigned short)v10[j]) +
                  wv.w * bf2f((unsigned short)v11[j]);
    }

    union { unsigned short s[8]; short8 v8; } o8;
#pragma unroll
    for (int j = 0; j < 8; ++j) o8.s[j] = f2bf(acc[j]);
    *(short8*)&samp[(size_t)p * 256 + g * 64 + sub * 8] = o8.v8;
  }
}

// ---------------------------------------------------------------------------
// Final GEMM: out[32768,256](fp32) = samp @ wo_b^T + b_out  (proven R5)
// ---------------------------------------------------------------------------
__global__ __launch_bounds__(256) void gemm_out(
    const unsigned short* __restrict__ A, const unsigned short* __restrict__ W,
    const float* __restrict__ bias, float* __restrict__ Cout) {
  __shared__ __align__(16) unsigned short As[128 * 32];
  __shared__ __align__(16) unsigned short Bs[128 * 32];
  int tid = threadIdx.x;
  int wave = tid >> 6, lane = tid & 63;
  int wr = wave >> 1, wc = wave & 1;

  int bid = blockIdx.x;
  int swz = (bid & 7) * 64 + (bid >> 3);
  size_t rowB = (size_t)(swz >> 1) * 128;
  int colB = (swz & 1) * 128;

  f32x4 acc[4][4];
#pragma unroll
  for (int m = 0; m < 4; ++m)
#pragma unroll
    for (int n = 0; n < 4; ++n) acc[m][n] = (f32x4)(0.f);

  int arow = lane >> 2;
  int acol = (lane & 3) * 8;

  for (int k0 = 0; k0 < 256; k0 += 32) {
#pragma unroll
    for (int jj = 0; jj < 2; ++jj) {
      int j = wave * 2 + jj;
      const unsigned short* ga = A + (rowB + 16 * j + arow) * 256 + k0 + acol;
      __builtin_amdgcn_global_load_lds(
          (const __attribute__((address_space(1))) unsigned int*)ga,
          (__attribute__((address_space(3))) unsigned int*)(As + j * 512),
          16, 0, 0);
      const unsigned short* gb =
          W + ((size_t)(colB + 16 * j + arow)) * 256 + k0 + acol;
      __builtin_amdgcn_global_load_lds(
          (const __attribute__((address_space(1))) unsigned int*)gb,
          (__attribute__((address_space(3))) unsigned int*)(Bs + j * 512),
          16, 0, 0);
    }
    __syncthreads();

    short8 aF[4], bF[4];
#pragma unroll
    for (int m = 0; m < 4; ++m)
      aF[m] = *(const short8*)&As[(wr * 64 + m * 16 + (lane & 15)) * 32 +
                                  (lane >> 4) * 8];
#pragma unroll
    for (int n = 0; n < 4; ++n)
      bF[n] = *(const short8*)&Bs[(wc * 64 + n * 16 + (lane & 15)) * 32 +
                                  (lane >> 4) * 8];
#pragma unroll
    for (int m = 0; m < 4; ++m)
#pragma unroll
      for (int n = 0; n < 4; ++n)
        acc[m][n] = __builtin_amdgcn_mfma_f32_16x16x32_bf16(
            aF[m], bF[n], acc[m][n], 0, 0, 0);
    __syncthreads();
  }

#pragma unroll
  for (int n = 0; n < 4; ++n) {
    int col = colB + wc * 64 + n * 16 + (lane & 15);
    float bv = bias[col];
#pragma unroll
    for (int m = 0; m < 4; ++m) {
#pragma unroll
      for (int j = 0; j < 4; ++j) {
        size_t row = rowB + wr * 64 + m * 16 + (lane >> 4) * 4 + j;
        Cout[row * 256 + col] = acc[m][n][j] + bv;
      }
    }
  }
}

// ---------------------------------------------------------------------------
extern "C" void kernel_launch(void* const* d_in, const int* in_sizes, int n_in,
                              void* d_out, int out_size, void* d_ws,
                              size_t ws_size, hipStream_t stream) {
  const float* x     = (const float*)d_in[0];
  const float* w_in  = (const float*)d_in[3];
  const float* b_in  = (const float*)d_in[4];
  const float* w_out = (const float*)d_in[5];
  const float* b_out = (const float*)d_in[6];
  const float* w_dw  = (const float*)d_in[7];
  const float* b_dw  = (const float*)d_in[8];
  const float* w_pw  = (const float*)d_in[9];
  const float* b_pw  = (const float*)d_in[10];
  float* out = (float*)d_out;
  char* ws = (char*)d_ws;

  unsigned short* xb    = (unsigned short*)(ws);                  // 16 MB
  unsigned short* dwb   = (unsigned short*)(ws + (16u << 20));    // 16 MB (dw -> samp)
  unsigned short* vproj = (unsigned short*)(ws + (32u << 20));    // 16 MB
  unsigned short* om    = (unsigned short*)(ws + (48u << 20));    // 8 MB (bf16, stride 128)
  unsigned short* wi_b  = (unsigned short*)(ws + (56u << 20));    // 128 KB
  unsigned short* wo_b  = (unsigned short*)(ws + (56u << 20) + (128u << 10));
  unsigned short* wp_b  = (unsigned short*)(ws + (56u << 20) + (256u << 10)); // 64 KB
  float*          bpw   = (float*)(ws + (56u << 20) + (320u << 10));          // 512 B

  prep_fused<<<8834, 256, 0, stream>>>(x, w_dw, b_dw, w_in, w_out, w_pw, b_pw,
                                       xb, dwb, wi_b, wo_b, wp_b, bpw);
  gemm_mid<<<768, 256, 0, stream>>>(dwb, wp_b, bpw, om, xb, wi_b, b_in, vproj);
  deform_sample_v5<<<2048, 256, 0, stream>>>(vproj, om, dwb /* samp */);
  gemm_out<<<512, 256, 0, stream>>>(dwb, wo_b, b_out, out);
}